// Round 7
// baseline (179.221 us; speedup 1.0000x reference)
//
#include <hip/hip_runtime.h>
#include <math.h>

#define NN   6464      // total nodes
#define NPER 101
#define HD   128
#define HE   16
#define NE   652864    // 64*101*101
#define PERB 10201     // 101*101
#define EPSB 1e-5f
#define SLOPE 0.2f
#define TI   4         // dest nodes per attention block
#define NBLK 26        // ceil(101/4)
#define L2E  1.44269504088896340736f
#define NO   384       // t|U|V concatenated output width

__global__ void k_zero(float* p, int n){
    int i = blockIdx.x*blockDim.x + threadIdx.x;
    if (i < n) p[i] = 0.f;
}

__global__ void k_reduce_eai(const float* __restrict__ eai, float* __restrict__ stats){
    __shared__ float ls[256], ls2[256];
    float s = 0.f, s2 = 0.f;
    for (int i = blockIdx.x*256 + threadIdx.x; i < NE; i += gridDim.x*256){
        float v = eai[i]; s += v; s2 += v*v;
    }
    int tid = threadIdx.x;
    ls[tid] = s; ls2[tid] = s2; __syncthreads();
    for (int o = 128; o > 0; o >>= 1){
        if (tid < o){ ls[tid] += ls[tid+o]; ls2[tid] += ls2[tid+o]; }
        __syncthreads();
    }
    if (tid == 0){ atomicAdd(&stats[0], ls[0]); atomicAdd(&stats[1], ls2[0]); }
}

// c1[h], dv[h] per layer from edge-attr batch stats (both pre-scaled by L2E).
__global__ void k_setup(const float* __restrict__ stats, const float* __restrict__ few,
                        const float* __restrict__ beg, const float* __restrict__ beb,
                        const float* __restrict__ attn_w, const float* __restrict__ attn_b,
                        float* __restrict__ c1, float* __restrict__ dv){
    __shared__ float sA[HE], sB[HE];
    int tid = threadIdx.x;                 // 128 threads = h
    float mean = stats[0] * (1.f/NE);
    float var  = stats[1] * (1.f/NE) - mean*mean;
    if (tid < HE){
        float w = few[tid];
        float a = w * rsqrtf(var*w*w + EPSB) * beg[tid];
        sA[tid] = a; sB[tid] = beb[tid] - mean*a;
    }
    __syncthreads();
    for (int l = 0; l < 3; l++){
        const float* W = attn_w + (l*272 + 256)*HD;   // We rows (256..271)
        float a1 = 0.f, a2 = 0.f;
        for (int k = 0; k < HE; k++){
            float wv = W[k*HD + tid];
            a1 += sA[k]*wv; a2 += sB[k]*wv;
        }
        c1[l*HD + tid] = a1 * L2E;
        dv[l*HD + tid] = (a2 + attn_b[l*HD + tid]) * L2E;
    }
}

// Build Wcat[l][k][384] = [ F | (F@Wi)*L2E | (F@Wj)*L2E ]; bias row r==128
// adds (fc_b@Wi + fc_b@Wj)*L2E into dv (t-bias handled in k_gemm's acc init).
__global__ __launch_bounds__(128) void k_comp(const float* __restrict__ fc_w, const float* __restrict__ fc_b,
                     const float* __restrict__ attn_w, float* __restrict__ Wcat, float* __restrict__ dv){
    int blk = blockIdx.x;
    int l = blk / 129, r = blk - l*129;
    int hh = threadIdx.x;
    const float* Wi = attn_w + (size_t)l*272*HD;
    const float* Wj = Wi + HD*HD;
    const float* Fr = (r < HD) ? (fc_w + (size_t)l*HD*HD + (size_t)r*HD) : (fc_b + l*HD);
    float ai = 0.f, aj = 0.f;
    for (int m = 0; m < HD; m++){
        float f = Fr[m];
        ai = fmaf(f, Wi[m*HD + hh], ai);
        aj = fmaf(f, Wj[m*HD + hh], aj);
    }
    if (r < HD){
        float* row = Wcat + ((size_t)l*HD + r)*NO;
        row[hh]        = Fr[hh];          // F copy (t-part)
        row[HD  + hh]  = ai * L2E;        // CWi
        row[2*HD + hh] = aj * L2E;        // CWj
    } else {
        dv[l*HD + hh] += (ai + aj) * L2E;
    }
}

// h0 = [x,demand] @ fc_node_w + b, training-mode BatchNorm over all N rows.
__global__ __launch_bounds__(256) void k_node_bn(const float* __restrict__ x, const float* __restrict__ demand,
                          const float* __restrict__ w, const float* __restrict__ b,
                          const float* __restrict__ g, const float* __restrict__ beta,
                          float* __restrict__ hbuf){
    int k = blockIdx.x, tid = threadIdx.x;
    float w0 = w[k], w1 = w[HD+k], w2 = w[2*HD+k], bb = b[k];
    float s = 0.f, s2 = 0.f;
    for (int n = tid; n < NN; n += 256){
        float p = x[2*n]*w0 + x[2*n+1]*w1 + demand[n]*w2 + bb;
        s += p; s2 += p*p;
    }
    __shared__ float ls[256], ls2[256];
    ls[tid] = s; ls2[tid] = s2; __syncthreads();
    for (int o = 128; o > 0; o >>= 1){
        if (tid < o){ ls[tid] += ls[tid+o]; ls2[tid] += ls2[tid+o]; }
        __syncthreads();
    }
    __shared__ float smu, srs;
    if (tid == 0){
        float mu = ls[0]*(1.f/NN);
        float var = ls2[0]*(1.f/NN) - mu*mu;
        smu = mu; srs = rsqrtf(var + EPSB);
    }
    __syncthreads();
    float mu = smu, rs = srs, gg = g[k], be = beta[k];
    for (int n = tid; n < NN; n += 256){
        float p = x[2*n]*w0 + x[2*n+1]*w1 + demand[n]*w2 + bb;
        hbuf[n*HD + k] = (p - mu)*rs*gg + be;
    }
}

// Transpose eai into block-friendly layout: esT[b][c][j][k] = eai[b, j, c*4+k].
// Input-coalesced; scattered writes absorbed by L2.
__global__ __launch_bounds__(256) void k_prep_es(const float* __restrict__ eai, float* __restrict__ esT){
    int b = blockIdx.x;
    const float* src = eai + (size_t)b*PERB;
    float* dst = esT + (size_t)b*NBLK*NPER*4;
    for (int ji = threadIdx.x; ji < PERB; ji += 256){
        int j = ji / NPER, i = ji - j*NPER;
        dst[(((size_t)(i >> 2))*NPER + j)*4 + (i & 3)] = src[ji];
    }
}

// Tiled GEMM: TUV[6464][384] = hbuf[6464][128] @ Wcat_l[128][384] (+ fc_b on t-tile).
// 64x128 tile, thread = 4m x (4+4)n, BK=16, LDS ping-pong double-buffer.
#define BM 64
#define BN 128
#define BK 16
__global__ __launch_bounds__(256) void k_gemm(const float* __restrict__ hbuf,
                     const float* __restrict__ Wcat, const float* __restrict__ fc_b,
                     float* __restrict__ TUV, int l){
    __shared__ float As[2][BK][68];
    __shared__ float Bs[2][BK][BN];
    int bi = blockIdx.x;
    int bm = bi / 3, bn = bi - bm*3;
    int m0 = bm*BM, o0 = bn*BN;
    int tid = threadIdx.x;
    int tx = tid & 15, ty = tid >> 4;
    const float* Wl = Wcat + (size_t)l*HD*NO;

    float acc[4][8];
    #pragma unroll
    for (int i = 0; i < 4; i++)
        #pragma unroll
        for (int j = 0; j < 8; j++) acc[i][j] = 0.f;
    if (bn == 0){
        const float* fb = fc_b + l*HD;
        #pragma unroll
        for (int j = 0; j < 4; j++){
            float b0 = fb[4*tx + j], b1 = fb[64 + 4*tx + j];
            #pragma unroll
            for (int i = 0; i < 4; i++){ acc[i][j] = b0; acc[i][j+4] = b1; }
        }
    }

    int ar = tid >> 2, ac4 = tid & 3;
    int bq0 = tid, bq1 = tid + 256;
    int bc0 = bq0 >> 5, bn40 = bq0 & 31;
    int bc1 = bq1 >> 5, bn41 = bq1 & 31;

    float4 ra  = *(const float4*)&hbuf[(size_t)(m0 + ar)*HD + 4*ac4];
    float4 rb0 = *(const float4*)&Wl[(size_t)bc0*NO + o0 + 4*bn40];
    float4 rb1 = *(const float4*)&Wl[(size_t)bc1*NO + o0 + 4*bn41];
    As[0][4*ac4+0][ar] = ra.x; As[0][4*ac4+1][ar] = ra.y;
    As[0][4*ac4+2][ar] = ra.z; As[0][4*ac4+3][ar] = ra.w;
    *(float4*)&Bs[0][bc0][4*bn40] = rb0;
    *(float4*)&Bs[0][bc1][4*bn41] = rb1;
    __syncthreads();

    for (int ch = 0; ch < 8; ch++){
        int p = ch & 1;
        if (ch < 7){
            int k0 = (ch+1)*BK;
            ra  = *(const float4*)&hbuf[(size_t)(m0 + ar)*HD + k0 + 4*ac4];
            rb0 = *(const float4*)&Wl[(size_t)(k0 + bc0)*NO + o0 + 4*bn40];
            rb1 = *(const float4*)&Wl[(size_t)(k0 + bc1)*NO + o0 + 4*bn41];
        }
        #pragma unroll
        for (int c = 0; c < BK; c++){
            float4 av  = *(const float4*)&As[p][c][4*ty];
            float4 bv0 = *(const float4*)&Bs[p][c][4*tx];
            float4 bv1 = *(const float4*)&Bs[p][c][64 + 4*tx];
            float a[4] = {av.x, av.y, av.z, av.w};
            float b[8] = {bv0.x, bv0.y, bv0.z, bv0.w, bv1.x, bv1.y, bv1.z, bv1.w};
            #pragma unroll
            for (int i = 0; i < 4; i++)
                #pragma unroll
                for (int j = 0; j < 8; j++)
                    acc[i][j] = fmaf(a[i], b[j], acc[i][j]);
        }
        if (ch < 7){
            int pn = p ^ 1;
            As[pn][4*ac4+0][ar] = ra.x; As[pn][4*ac4+1][ar] = ra.y;
            As[pn][4*ac4+2][ar] = ra.z; As[pn][4*ac4+3][ar] = ra.w;
            *(float4*)&Bs[pn][bc0][4*bn40] = rb0;
            *(float4*)&Bs[pn][bc1][4*bn41] = rb1;
            __syncthreads();
        }
    }
    #pragma unroll
    for (int i = 0; i < 4; i++){
        size_t row = (size_t)(m0 + 4*ty + i)*NO + o0;
        *(float4*)&TUV[row + 4*tx]      = make_float4(acc[i][0], acc[i][1], acc[i][2], acc[i][3]);
        *(float4*)&TUV[row + 64 + 4*tx] = make_float4(acc[i][4], acc[i][5], acc[i][6], acc[i][7]);
    }
}

// Attention core: CNT rows, all indices compile-time (no clamps, no 64-bit muls
// in the loop). rowp -> t at +0, V at +256 floats (same TUV row). 2-chunk pipeline.
template<int CNT>
__device__ __forceinline__ void attn_core(const float* rowp, const float4* esp,
                                          float2 c1h, const float2* base,
                                          float2* s, float2* acc){
    constexpr int NCH = (CNT + 3) / 4;
    float2 tA[4], vA[4], tB[4], vB[4];
    #pragma unroll
    for (int r = 0; r < 4; ++r){
        if (r < CNT){
            tA[r] = *(const float2*)(rowp + r*NO);
            vA[r] = *(const float2*)(rowp + r*NO + 2*HD);
        }
    }
    #pragma unroll
    for (int ch = 0; ch < NCH; ++ch){
        const int jb = ch*4;
        #pragma unroll
        for (int r = 0; r < 4; ++r){
            const int jn = jb + 4 + r;
            if (jn < CNT){
                tB[r] = *(const float2*)(rowp + jn*NO);
                vB[r] = *(const float2*)(rowp + jn*NO + 2*HD);
            }
        }
        #pragma unroll
        for (int r = 0; r < 4; ++r){
            const int j = jb + r;
            if (j < CNT){
                const float4 e4 = esp[j];
                const float ev[4] = {e4.x, e4.y, e4.z, e4.w};
                const float2 vj = vA[r], tj = tA[r];
                #pragma unroll
                for (int k = 0; k < TI; ++k){
                    float bx = base[k].x + vj.x;
                    float by = base[k].y + vj.y;
                    float zx = fmaf(ev[k], c1h.x, bx);
                    float zy = fmaf(ev[k], c1h.y, by);
                    zx = fmaxf(zx, SLOPE*zx);
                    zy = fmaxf(zy, SLOPE*zy);
                    float wx = __builtin_amdgcn_exp2f(zx);
                    float wy = __builtin_amdgcn_exp2f(zy);
                    s[k].x += wx; s[k].y += wy;
                    acc[k].x = fmaf(wx, tj.x, acc[k].x);
                    acc[k].y = fmaf(wy, tj.y, acc[k].y);
                }
            }
        }
        #pragma unroll
        for (int r = 0; r < 4; ++r){ tA[r] = tB[r]; vA[r] = vB[r]; }
    }
}

// Attention v7: 512 threads = 8 waves; waves 0-6 own 13 j-rows, wave 7 owns 10.
// Compile-time trip counts; es slab pre-transposed (coalesced LDS stage).
__global__ __launch_bounds__(512) void k_attn7(const float* __restrict__ TUV,
                      const float* __restrict__ esT,
                      const float* __restrict__ c1, const float* __restrict__ dv,
                      float* __restrict__ hbuf, int l, float* __restrict__ outp){
    __shared__ float4 es4[NPER];
    __shared__ float ps[8][TI][HD], pa[8][TI][HD];
    int blk = blockIdx.x;
    int xcd = blk & 7, r = blk >> 3;       // XCD-aware swizzle (bijective)
    int b = xcd + 8*(r & 7), c = r >> 3;
    int i0 = c*TI;
    int tid = threadIdx.x;
    int q = tid & 63, jg = tid >> 6;
    int h0 = 2*q;

    const float* ep = esT + ((size_t)(b*NBLK + c)*NPER)*4;
    for (int idx = tid; idx < NPER*4; idx += 512)
        ((float*)es4)[idx] = ep[idx];

    float2 c1h = *(const float2*)&c1[l*HD + h0];
    float2 dd  = *(const float2*)&dv[l*HD + h0];
    float2 base[TI], s[TI], acc[TI];
    #pragma unroll
    for (int k = 0; k < TI; k++){
        int i = i0 + k; if (i > NPER-1) i = NPER-1;
        float2 uu = *(const float2*)&TUV[(size_t)(b*NPER + i)*NO + HD + h0];
        base[k].x = uu.x + dd.x; base[k].y = uu.y + dd.y;
        s[k].x = 0.f; s[k].y = 0.f; acc[k].x = 0.f; acc[k].y = 0.f;
    }
    __syncthreads();

    const float* rowp = TUV + (size_t)(b*NPER + jg*13)*NO + h0;
    const float4* esp = es4 + jg*13;
    if (jg < 7) attn_core<13>(rowp, esp, c1h, base, s, acc);
    else        attn_core<10>(rowp, esp, c1h, base, s, acc);

    #pragma unroll
    for (int k = 0; k < TI; k++){
        *(float2*)&ps[jg][k][h0] = s[k];
        *(float2*)&pa[jg][k][h0] = acc[k];
    }
    __syncthreads();
    {
        int k = tid >> 7, h = tid & (HD-1);
        int i = i0 + k;
        if (i < NPER){
            float st = 0.f, at = 0.f;
            #pragma unroll
            for (int g = 0; g < 8; g++){ st += ps[g][k][h]; at += pa[g][k][h]; }
            size_t o = (size_t)(b*NPER + i)*HD + h;
            float res = fmaf(at, __builtin_amdgcn_rcpf(st + 1e-16f), hbuf[o]);
            hbuf[o] = res;
            if (outp) outp[o] = res;
        }
    }
}

extern "C" void kernel_launch(void* const* d_in, const int* in_sizes, int n_in,
                              void* d_out, int out_size, void* d_ws, size_t ws_size,
                              hipStream_t stream) {
    const float* x      = (const float*)d_in[0];
    const float* demand = (const float*)d_in[1];
    const float* eai    = (const float*)d_in[2];
    // d_in[3] edge_index: known constant structure, unused
    const float* fnw = (const float*)d_in[4];
    const float* fnb = (const float*)d_in[5];
    const float* bng = (const float*)d_in[6];
    const float* bnb = (const float*)d_in[7];
    const float* few = (const float*)d_in[8];
    // d_in[9] fc_edge_b cancels in BatchNorm
    const float* beg = (const float*)d_in[10];
    const float* beb = (const float*)d_in[11];
    const float* fcw = (const float*)d_in[12];
    const float* fcb = (const float*)d_in[13];
    const float* aw  = (const float*)d_in[14];
    const float* ab  = (const float*)d_in[15];
    float* out = (float*)d_out;

    float* w     = (float*)d_ws;
    float* hbuf  = w;                          // NN*128
    float* TUV   = w + (size_t)NN*HD;          // NN*384
    float* esT   = TUV + (size_t)NN*NO;        // 64*26*101*4
    float* stats = esT + (size_t)64*NBLK*NPER*4; // 4
    float* c1    = stats + 4;                  // 3*128
    float* dv    = c1 + 3*HD;                  // 3*128
    float* Wcat  = dv + 3*HD;                  // 3*128*384

    hipLaunchKernelGGL(k_zero, dim3(1), dim3(64), 0, stream, stats, 4);
    hipLaunchKernelGGL(k_reduce_eai, dim3(256), dim3(256), 0, stream, eai, stats);
    hipLaunchKernelGGL(k_setup, dim3(1), dim3(HD), 0, stream, stats, few, beg, beb, aw, ab, c1, dv);
    hipLaunchKernelGGL(k_comp, dim3(3*129), dim3(HD), 0, stream, fcw, fcb, aw, Wcat, dv);
    hipLaunchKernelGGL(k_node_bn, dim3(HD), dim3(256), 0, stream, x, demand, fnw, fnb, bng, bnb, hbuf);
    hipLaunchKernelGGL(k_prep_es, dim3(64), dim3(256), 0, stream, eai, esT);
    for (int l = 0; l < 3; l++){
        hipLaunchKernelGGL(k_gemm, dim3(101*3), dim3(256), 0, stream,
                           hbuf, Wcat, fcb, TUV, l);
        hipLaunchKernelGGL(k_attn7, dim3(64*NBLK), dim3(512), 0, stream,
                           TUV, esT, c1, dv, hbuf, l, (l == 2) ? out : (float*)nullptr);
    }
}